// Round 3
// baseline (382.472 us; speedup 1.0000x reference)
//
#include <hip/hip_runtime.h>
#include <cstdint>

// Problem constants
#define Bn   32
#define Cn   256
#define Hn   56
#define Wn   56
#define HWn  (Hn*Wn)           // 3136
#define NPIX (Bn*HWn)          // 100352
#define WELEMS (Cn*Cn*9)       // 589824
#define EPSv 1e-5f

// padded channels-last activation plane: [b][58 rows][58 cols][256 ci] i8
// per-pixel 256B block stored XOR-swizzled: 16B slot s lives at s ^ (padded_col & 15)
#define PR   58
#define PPLANE (PR*PR)         // 3364

// ws layout (bytes)
#define F_WABS  0              // float index
#define F_SUM   64             // float[256]
#define F_SQ    320            // float[256]
#define STATS_BYTES 4096
#define WPK_OFF  4096                     // i8 wpk[kc=36][co=256][64]  (A repack)
#define WPK_BYTES WELEMS                  // 589824
#define ACT_OFF  (WPK_OFF + WPK_BYTES)    // 593920 (16B aligned)
#define ACT_BYTES (Bn*PPLANE*Cn)          // 27553792

typedef int v4i __attribute__((ext_vector_type(4)));

// ---------------------------------------------------------------------------
// Fused packing kernel.
// Blocks 0..391: pack activations (+ zero the padding halo with the first
//   7296 threads — only the halo needs zeroing, interior is fully written).
// Blocks 392..427: repack weights to A-GEMM layout
//   wpk[(kc*256 + co)*64 + cb], kc = t*4+s, cb = ci - s*64, sign in {+1,-1},
//   and reduce sum(|clip(w,-1,1)|) into wsf[F_WABS].
__global__ void pack_all(const float* __restrict__ x,
                         const float* __restrict__ w,
                         float* __restrict__ wsf,
                         uint8_t* __restrict__ wpk,
                         uint8_t* __restrict__ act) {
    if (blockIdx.x < 392) {
        int v = blockIdx.x * 256 + threadIdx.x;   // 0..100351
        // --- halo zeroing: 32 batches * 228 border pixels = 7296 ---
        if (v < 7296) {
            int b = v / 228;
            int r = v - b * 228;
            int y, xx;
            if (r < 58)       { y = 0;  xx = r; }
            else if (r < 116) { y = 57; xx = r - 58; }
            else { int r2 = r - 116; y = 1 + (r2 >> 1); xx = (r2 & 1) * 57; }
            uint4* d = (uint4*)(act + ((size_t)(b * PR + y) * PR + xx) * 256);
            uint4 z = make_uint4(0, 0, 0, 0);
            #pragma unroll
            for (int i = 0; i < 16; i++) d[i] = z;
        }
        // --- interior pack with per-pixel XOR swizzle ---
        int b = v / HWn;
        int p = v - b * HWn;
        int y = p / Wn;
        int xx = p - y * Wn;
        const float* xp = x + (size_t)b * Cn * HWn + p;
        int key = (xx + 1) & 15;
        uint32_t* dst = (uint32_t*)(act + ((size_t)(b * PR + (y + 1)) * PR + (xx + 1)) * 256);
        #pragma unroll
        for (int slot = 0; slot < 16; slot++) {
            uint32_t rr[4];
            #pragma unroll
            for (int cw = 0; cw < 4; cw++) {
                uint32_t r = 0;
                #pragma unroll
                for (int j = 0; j < 4; j++) {
                    uint32_t sgn = __float_as_uint(xp[(size_t)(slot * 16 + cw * 4 + j) * HWn]) >> 31;
                    r |= (sgn ? 0xFFu : 0x01u) << (j * 8);
                }
                rr[cw] = r;
            }
            *(uint4*)(dst + (size_t)((slot ^ key) * 4)) = make_uint4(rr[0], rr[1], rr[2], rr[3]);
        }
    } else {
        int u = (blockIdx.x - 392) * 256 + threadIdx.x;   // 36*256 = 9216
        int co = u / 36;
        int kc = u - co * 36;
        int t  = kc >> 2;          // tap
        int s  = kc & 3;           // 64-ci chunk
        const float* wp = w + (size_t)co * 2304 + t;      // OIHW
        uint32_t* dst = (uint32_t*)(wpk + ((size_t)kc * 256 + co) * 64);
        float sabs = 0.0f;
        #pragma unroll
        for (int cw = 0; cw < 16; cw++) {
            uint32_t r = 0;
            #pragma unroll
            for (int j = 0; j < 4; j++) {
                int ci = s * 64 + cw * 4 + j;
                float wv = wp[(size_t)ci * 9];
                sabs += fminf(fabsf(wv), 1.0f);
                r |= ((__float_as_uint(wv) >> 31) ? 0xFFu : 0x01u) << (j * 8);
            }
            dst[cw] = r;
        }
        #pragma unroll
        for (int off = 32; off; off >>= 1) sabs += __shfl_down(sabs, off);
        __shared__ float sh[4];
        if ((threadIdx.x & 63) == 0) sh[threadIdx.x >> 6] = sabs;
        __syncthreads();
        if (threadIdx.x == 0)
            atomicAdd(&wsf[F_WABS], sh[0] + sh[1] + sh[2] + sh[3]);
    }
}

// ---------------------------------------------------------------------------
// Binary conv as implicit GEMM on the i8 matrix pipe, LDS-staged B.
// Block = (batch b, output row-pair): N-tile = 112 pixels, M = 256.
// 4 waves, wave w owns co in [w*64, w*64+64): 4 M-frags x 7 N-frags of
// mfma_i32_16x16x64_i8.  K-loop = 9 taps x 4 chunks of 64 ci, FULLY UNROLLED
// into one straight-line body so the scheduler can hoist the global A-loads
// and LDS B-reads across tap boundaries (counted vmcnt/lgkmcnt pipelining) —
// round-2 showed the runtime loop left the pipe 84% idle at 92 VGPRs.
// Epilogue: out = mean*dot + x, fused BN-stats via shfl_xor + atomics.
__global__ __launch_bounds__(256, 2) void conv_mfma(
    const uint8_t* __restrict__ act, const uint8_t* __restrict__ wpk,
    const float* __restrict__ x, float* __restrict__ wsf,
    float* __restrict__ out) {
    __shared__ uint4 ldsv[3712];              // 59392 B
    uint8_t* lds = (uint8_t*)ldsv;

    const int tid  = threadIdx.x;
    const int lane = tid & 63;
    const int wid  = tid >> 6;                // 0..3
    const int l15  = lane & 15;
    const int l4   = lane >> 4;               // 0..3

    const int bx = blockIdx.x;                // 0..895
    const int b  = bx / 28;
    const int y0 = (bx - b * 28) * 2;         // first output image row

    // Stage padded rows y0..y0+3 = one contiguous 59392B block of act.
    {
        const uint4* src = (const uint4*)(act + ((size_t)b * PR + y0) * PR * 256);
        for (int i = tid; i < 3712; i += 256) ldsv[i] = src[i];
    }
    __syncthreads();

    // Per-N-fragment pixel bookkeeping (pixel n = ni*16 + l15, n in [0,112)).
    int rr1[7], cc1[7], obn[7];
    #pragma unroll
    for (int ni = 0; ni < 7; ni++) {
        int n  = ni * 16 + l15;
        int r_ = n / 56;
        int c_ = n - r_ * 56;
        rr1[ni] = r_ + 1;      // staged-local row of center (stage holds rows -1..+2)
        cc1[ni] = c_ + 1;      // padded col of center
        obn[ni] = n;
    }
    // A-fragment lane offset (co = wid*64 + mi*16 + l15, bytes l4*16)
    const int aoffb = (wid * 64 + l15) * 64 + l4 * 16;

    v4i acc[4][7] = {};

    #pragma unroll
    for (int t = 0; t < 9; t++) {
        const int dh = t / 3 - 1;
        const int dw = t % 3 - 1;
        int pixb[7], key[7];
        #pragma unroll
        for (int ni = 0; ni < 7; ni++) {
            int lc = cc1[ni] + dw;
            pixb[ni] = ((rr1[ni] + dh) * 58 + lc) * 256;
            key[ni]  = lc & 15;
        }
        #pragma unroll
        for (int s = 0; s < 4; s++) {
            const int kc = t * 4 + s;
            v4i af[4];
            #pragma unroll
            for (int mi = 0; mi < 4; mi++)
                af[mi] = *(const v4i*)(wpk + (size_t)kc * 16384 + mi * 1024 + aoffb);
            v4i bf[7];
            #pragma unroll
            for (int ni = 0; ni < 7; ni++)
                bf[ni] = *(const v4i*)(lds + pixb[ni] + (((s * 4 + l4) ^ key[ni]) << 4));
            #pragma unroll
            for (int mi = 0; mi < 4; mi++) {
                #pragma unroll
                for (int ni = 0; ni < 7; ni++)
                    acc[mi][ni] = __builtin_amdgcn_mfma_i32_16x16x64_i8(
                        af[mi], bf[ni], acc[mi][ni], 0, 0, 0);
            }
        }
    }

    const float mv = wsf[F_WABS] * (1.0f / (float)WELEMS);
    const int co_w = wid * 64;
    const int pbase = b * (Cn * HWn) + y0 * 56;

    // Epilogue: scale + shortcut + store + per-channel partial stats.
    float ssum[4][4] = {}, ssq[4][4] = {};
    #pragma unroll
    for (int mi = 0; mi < 4; mi++) {
        #pragma unroll
        for (int ni = 0; ni < 7; ni++) {
            v4i a = acc[mi][ni];
            #pragma unroll
            for (int q = 0; q < 4; q++) {
                int co = co_w + mi * 16 + l4 * 4 + q;
                size_t idx = (size_t)pbase + (size_t)co * HWn + obn[ni];
                float val = fmaf(mv, (float)a[q], x[idx]);
                out[idx] = val;
                ssum[mi][q] += val;
                ssq[mi][q]  += val * val;
            }
        }
    }
    // Reduce across the 16 lanes (l15) sharing each channel, then atomics.
    #pragma unroll
    for (int mi = 0; mi < 4; mi++) {
        #pragma unroll
        for (int q = 0; q < 4; q++) {
            float s = ssum[mi][q], sq = ssq[mi][q];
            #pragma unroll
            for (int off = 1; off < 16; off <<= 1) {
                s  += __shfl_xor(s, off);
                sq += __shfl_xor(sq, off);
            }
            if (l15 == 0) {
                int co = co_w + mi * 16 + l4 * 4 + q;
                atomicAdd(&wsf[F_SUM + co], s);
                atomicAdd(&wsf[F_SQ  + co], sq);
            }
        }
    }
}

// ---------------------------------------------------------------------------
// BN finalize (per-plane, from fused stats) + normalize + ReLU, in place.
__global__ void epilogue_kernel(float* __restrict__ out,
                                const float* __restrict__ wsf,
                                const float* __restrict__ g,
                                const float* __restrict__ bt) {
    int plane = blockIdx.x;   // b*256 + c
    int c = plane & 255;
    const float n = (float)(Bn * HWn);
    float mean = wsf[F_SUM + c] / n;
    float var  = wsf[F_SQ + c] / n - mean * mean;
    float sc = g[c] * rsqrtf(var + EPSv);
    float sh = bt[c] - mean * sc;
    float4* o4 = (float4*)(out + (size_t)plane * HWn);
    for (int i = threadIdx.x; i < HWn / 4; i += 256) {
        float4 v = o4[i];
        v.x = fmaxf(fmaf(v.x, sc, sh), 0.0f);
        v.y = fmaxf(fmaf(v.y, sc, sh), 0.0f);
        v.z = fmaxf(fmaf(v.z, sc, sh), 0.0f);
        v.w = fmaxf(fmaf(v.w, sc, sh), 0.0f);
        o4[i] = v;
    }
}

// ---------------------------------------------------------------------------
extern "C" void kernel_launch(void* const* d_in, const int* in_sizes, int n_in,
                              void* d_out, int out_size, void* d_ws, size_t ws_size,
                              hipStream_t stream) {
    const float* x     = (const float*)d_in[0];
    const float* w     = (const float*)d_in[1];
    const float* gamma = (const float*)d_in[2];
    const float* beta  = (const float*)d_in[3];
    float* out = (float*)d_out;

    float*   wsf = (float*)d_ws;
    uint8_t* wpk = (uint8_t*)d_ws + WPK_OFF;
    uint8_t* act = (uint8_t*)d_ws + ACT_OFF;

    hipMemsetAsync(d_ws, 0, STATS_BYTES, stream);
    pack_all<<<dim3(428), dim3(256), 0, stream>>>(x, w, wsf, wpk, act);
    conv_mfma<<<dim3(896), dim3(256), 0, stream>>>(act, wpk, x, wsf, out);
    epilogue_kernel<<<dim3(Bn * Cn), dim3(256), 0, stream>>>(out, wsf, gamma, beta);
}

// Round 4
// 355.350 us; speedup vs baseline: 1.0763x; 1.0763x over previous
//
#include <hip/hip_runtime.h>
#include <cstdint>

// Problem constants
#define Bn   32
#define Cn   256
#define Hn   56
#define Wn   56
#define HWn  (Hn*Wn)           // 3136
#define NPIX (Bn*HWn)          // 100352
#define WELEMS (Cn*Cn*9)       // 589824
#define EPSv 1e-5f

// padded channels-last activation plane: [b][58 rows][58 cols][256 ci] i8
// per-pixel 256B block stored XOR-swizzled: 16B slot s lives at s ^ (padded_col & 15)
#define PR   58
#define PPLANE (PR*PR)         // 3364

// ws layout (bytes)
#define F_WABS  0              // float index
#define F_SUM   64             // float[256]
#define F_SQ    320            // float[256]
#define STATS_BYTES 4096
#define WPK_OFF  4096                     // i8 wpk[kc=36][co=256][64]  (A repack)
#define WPK_BYTES WELEMS                  // 589824
#define ACT_OFF  (WPK_OFF + WPK_BYTES)    // 593920 (16B aligned)
#define ACT_BYTES (Bn*PPLANE*Cn)          // 27553792

typedef int v4i __attribute__((ext_vector_type(4)));

// ---------------------------------------------------------------------------
// Fused packing kernel (unchanged from round 3 — verified).
__global__ void pack_all(const float* __restrict__ x,
                         const float* __restrict__ w,
                         float* __restrict__ wsf,
                         uint8_t* __restrict__ wpk,
                         uint8_t* __restrict__ act) {
    if (blockIdx.x < 392) {
        int v = blockIdx.x * 256 + threadIdx.x;   // 0..100351
        // --- halo zeroing: 32 batches * 228 border pixels = 7296 ---
        if (v < 7296) {
            int b = v / 228;
            int r = v - b * 228;
            int y, xx;
            if (r < 58)       { y = 0;  xx = r; }
            else if (r < 116) { y = 57; xx = r - 58; }
            else { int r2 = r - 116; y = 1 + (r2 >> 1); xx = (r2 & 1) * 57; }
            uint4* d = (uint4*)(act + ((size_t)(b * PR + y) * PR + xx) * 256);
            uint4 z = make_uint4(0, 0, 0, 0);
            #pragma unroll
            for (int i = 0; i < 16; i++) d[i] = z;
        }
        // --- interior pack with per-pixel XOR swizzle ---
        int b = v / HWn;
        int p = v - b * HWn;
        int y = p / Wn;
        int xx = p - y * Wn;
        const float* xp = x + (size_t)b * Cn * HWn + p;
        int key = (xx + 1) & 15;
        uint32_t* dst = (uint32_t*)(act + ((size_t)(b * PR + (y + 1)) * PR + (xx + 1)) * 256);
        #pragma unroll
        for (int slot = 0; slot < 16; slot++) {
            uint32_t rr[4];
            #pragma unroll
            for (int cw = 0; cw < 4; cw++) {
                uint32_t r = 0;
                #pragma unroll
                for (int j = 0; j < 4; j++) {
                    uint32_t sgn = __float_as_uint(xp[(size_t)(slot * 16 + cw * 4 + j) * HWn]) >> 31;
                    r |= (sgn ? 0xFFu : 0x01u) << (j * 8);
                }
                rr[cw] = r;
            }
            *(uint4*)(dst + (size_t)((slot ^ key) * 4)) = make_uint4(rr[0], rr[1], rr[2], rr[3]);
        }
    } else {
        int u = (blockIdx.x - 392) * 256 + threadIdx.x;   // 36*256 = 9216
        int co = u / 36;
        int kc = u - co * 36;
        int t  = kc >> 2;          // tap
        int s  = kc & 3;           // 64-ci chunk
        const float* wp = w + (size_t)co * 2304 + t;      // OIHW
        uint32_t* dst = (uint32_t*)(wpk + ((size_t)kc * 256 + co) * 64);
        float sabs = 0.0f;
        #pragma unroll
        for (int cw = 0; cw < 16; cw++) {
            uint32_t r = 0;
            #pragma unroll
            for (int j = 0; j < 4; j++) {
                int ci = s * 64 + cw * 4 + j;
                float wv = wp[(size_t)ci * 9];
                sabs += fminf(fabsf(wv), 1.0f);
                r |= ((__float_as_uint(wv) >> 31) ? 0xFFu : 0x01u) << (j * 8);
            }
            dst[cw] = r;
        }
        #pragma unroll
        for (int off = 32; off; off >>= 1) sabs += __shfl_down(sabs, off);
        __shared__ float sh[4];
        if ((threadIdx.x & 63) == 0) sh[threadIdx.x >> 6] = sabs;
        __syncthreads();
        if (threadIdx.x == 0)
            atomicAdd(&wsf[F_WABS], sh[0] + sh[1] + sh[2] + sh[3]);
    }
}

// ---------------------------------------------------------------------------
// Binary conv as implicit GEMM on the i8 matrix pipe, LDS-staged B,
// EXPLICIT 4-deep software pipeline on the global A-stream:
//   4 named register buffers af0..af3; step s consumes af<s> (kc = t*4+s) and
//   immediately re-issues its load for kc+4 (next tap, same ci-chunk).
//   Coverage = 3 MFMA blocks (~450 cyc) > L2 latency; compiler emits counted
//   vmcnt because the consuming MFMA is 3 steps downstream in program order.
// Runtime t-loop (no unroll) keeps I-cache small; s-steps are macro-unrolled
// so all buffer/register indices are compile-time constants.
// MFMA order ni-outer: first 4 MFMAs need only bf[0] -> fine lgkmcnt overlap.
__global__ __launch_bounds__(256, 2) void conv_mfma(
    const uint8_t* __restrict__ act, const uint8_t* __restrict__ wpk,
    const float* __restrict__ x, float* __restrict__ wsf,
    float* __restrict__ out) {
    __shared__ uint4 ldsv[3712];              // 59392 B
    uint8_t* lds = (uint8_t*)ldsv;

    const int tid  = threadIdx.x;
    const int lane = tid & 63;
    const int wid  = tid >> 6;                // 0..3
    const int l15  = lane & 15;
    const int l4   = lane >> 4;               // 0..3

    const int bx = blockIdx.x;                // 0..895
    const int b  = bx / 28;
    const int y0 = (bx - b * 28) * 2;         // first output image row

    // Stage padded rows y0..y0+3 = one contiguous 59392B block of act.
    {
        const uint4* src = (const uint4*)(act + ((size_t)b * PR + y0) * PR * 256);
        for (int i = tid; i < 3712; i += 256) ldsv[i] = src[i];
    }

    // Per-N-fragment pixel bookkeeping (pixel n = ni*16 + l15, n in [0,112)).
    // pixc = LDS byte offset of the window CENTER (local row r_+1, padded col c_+1).
    int pixc[7], cc1[7];
    #pragma unroll
    for (int ni = 0; ni < 7; ni++) {
        int n  = ni * 16 + l15;
        int r_ = n / 56;
        int c_ = n - r_ * 56;
        cc1[ni]  = c_ + 1;
        pixc[ni] = ((r_ + 1) * 58 + (c_ + 1)) * 256;
    }
    // A-fragment lane offset (co = wid*64 + mi*16 + l15, bytes l4*16)
    const uint8_t* abase = wpk + (wid * 64 + l15) * 64 + l4 * 16;

    // Pipeline prologue: fill the 4 A-buffers with kc = 0..3.
    v4i af0[4], af1[4], af2[4], af3[4];
    #pragma unroll
    for (int mi = 0; mi < 4; mi++) {
        af0[mi] = *(const v4i*)(abase + (size_t)0 * 16384 + mi * 1024);
        af1[mi] = *(const v4i*)(abase + (size_t)1 * 16384 + mi * 1024);
        af2[mi] = *(const v4i*)(abase + (size_t)2 * 16384 + mi * 1024);
        af3[mi] = *(const v4i*)(abase + (size_t)3 * 16384 + mi * 1024);
    }

    __syncthreads();

    v4i acc[4][7] = {};

#define STEP(S, AF)                                                            \
    {                                                                          \
        v4i bf[7];                                                             \
        _Pragma("unroll")                                                      \
        for (int ni = 0; ni < 7; ni++)                                         \
            bf[ni] = *(const v4i*)(lds + pixb[ni] +                            \
                                   ((((S) * 4 + l4) ^ key[ni]) << 4));         \
        _Pragma("unroll")                                                      \
        for (int ni = 0; ni < 7; ni++) {                                       \
            _Pragma("unroll")                                                  \
            for (int mi = 0; mi < 4; mi++)                                     \
                acc[mi][ni] = __builtin_amdgcn_mfma_i32_16x16x64_i8(           \
                    AF[mi], bf[ni], acc[mi][ni], 0, 0, 0);                     \
        }                                                                      \
        {                                                                      \
            int kcn = t4 + (S) + 4;                                            \
            kcn = kcn > 35 ? 35 : kcn;   /* tail: redundant reload, unused */  \
            const uint8_t* ap = abase + (size_t)kcn * 16384;                   \
            _Pragma("unroll")                                                  \
            for (int mi = 0; mi < 4; mi++)                                     \
                AF[mi] = *(const v4i*)(ap + mi * 1024);                        \
        }                                                                      \
    }

    #pragma unroll 1
    for (int t = 0; t < 9; t++) {
        const int dh = t / 3 - 1;
        const int dw = t % 3 - 1;
        const int toff = (dh * 58 + dw) * 256;
        const int t4 = t * 4;
        int pixb[7], key[7];
        #pragma unroll
        for (int ni = 0; ni < 7; ni++) {
            pixb[ni] = pixc[ni] + toff;
            key[ni]  = (cc1[ni] + dw) & 15;
        }
        STEP(0, af0)
        STEP(1, af1)
        STEP(2, af2)
        STEP(3, af3)
    }
#undef STEP

    const float mv = wsf[F_WABS] * (1.0f / (float)WELEMS);
    const int co_w = wid * 64;
    const int pbase = b * (Cn * HWn) + y0 * 56;

    // Epilogue: scale + shortcut + store + per-channel partial stats.
    float ssum[4][4] = {}, ssq[4][4] = {};
    #pragma unroll
    for (int mi = 0; mi < 4; mi++) {
        #pragma unroll
        for (int ni = 0; ni < 7; ni++) {
            v4i a = acc[mi][ni];
            #pragma unroll
            for (int q = 0; q < 4; q++) {
                int co = co_w + mi * 16 + l4 * 4 + q;
                size_t idx = (size_t)pbase + (size_t)co * HWn + (ni * 16 + l15);
                float val = fmaf(mv, (float)a[q], x[idx]);
                out[idx] = val;
                ssum[mi][q] += val;
                ssq[mi][q]  += val * val;
            }
        }
    }
    // Reduce across the 16 lanes (l15) sharing each channel, then atomics.
    #pragma unroll
    for (int mi = 0; mi < 4; mi++) {
        #pragma unroll
        for (int q = 0; q < 4; q++) {
            float s = ssum[mi][q], sq = ssq[mi][q];
            #pragma unroll
            for (int off = 1; off < 16; off <<= 1) {
                s  += __shfl_xor(s, off);
                sq += __shfl_xor(sq, off);
            }
            if (l15 == 0) {
                int co = co_w + mi * 16 + l4 * 4 + q;
                atomicAdd(&wsf[F_SUM + co], s);
                atomicAdd(&wsf[F_SQ  + co], sq);
            }
        }
    }
}

// ---------------------------------------------------------------------------
// BN finalize (per-plane, from fused stats) + normalize + ReLU, in place.
__global__ void epilogue_kernel(float* __restrict__ out,
                                const float* __restrict__ wsf,
                                const float* __restrict__ g,
                                const float* __restrict__ bt) {
    int plane = blockIdx.x;   // b*256 + c
    int c = plane & 255;
    const float n = (float)(Bn * HWn);
    float mean = wsf[F_SUM + c] / n;
    float var  = wsf[F_SQ + c] / n - mean * mean;
    float sc = g[c] * rsqrtf(var + EPSv);
    float sh = bt[c] - mean * sc;
    float4* o4 = (float4*)(out + (size_t)plane * HWn);
    for (int i = threadIdx.x; i < HWn / 4; i += 256) {
        float4 v = o4[i];
        v.x = fmaxf(fmaf(v.x, sc, sh), 0.0f);
        v.y = fmaxf(fmaf(v.y, sc, sh), 0.0f);
        v.z = fmaxf(fmaf(v.z, sc, sh), 0.0f);
        v.w = fmaxf(fmaf(v.w, sc, sh), 0.0f);
        o4[i] = v;
    }
}

// ---------------------------------------------------------------------------
extern "C" void kernel_launch(void* const* d_in, const int* in_sizes, int n_in,
                              void* d_out, int out_size, void* d_ws, size_t ws_size,
                              hipStream_t stream) {
    const float* x     = (const float*)d_in[0];
    const float* w     = (const float*)d_in[1];
    const float* gamma = (const float*)d_in[2];
    const float* beta  = (const float*)d_in[3];
    float* out = (float*)d_out;

    float*   wsf = (float*)d_ws;
    uint8_t* wpk = (uint8_t*)d_ws + WPK_OFF;
    uint8_t* act = (uint8_t*)d_ws + ACT_OFF;

    hipMemsetAsync(d_ws, 0, STATS_BYTES, stream);
    pack_all<<<dim3(428), dim3(256), 0, stream>>>(x, w, wsf, wpk, act);
    conv_mfma<<<dim3(896), dim3(256), 0, stream>>>(act, wpk, x, wsf, out);
    epilogue_kernel<<<dim3(Bn * Cn), dim3(256), 0, stream>>>(out, wsf, gamma, beta);
}